// Round 4
// baseline (486.079 us; speedup 1.0000x reference)
//
#include <hip/hip_runtime.h>
#include <hip/hip_bf16.h>

#define SEQ 4096
#define NB 2
#define DM 512
#define NH 8
#define DK 64

typedef __bf16 bf16;
typedef __bf16 bf16x4 __attribute__((ext_vector_type(4)));
typedef __bf16 bf16x8 __attribute__((ext_vector_type(8)));
typedef float  f32x4 __attribute__((ext_vector_type(4)));

__device__ __forceinline__ f32x4 mfma16(bf16x8 a, bf16x8 b, f32x4 c) {
    return __builtin_amdgcn_mfma_f32_16x16x32_bf16(a, b, c, 0, 0, 0);
}

__device__ __forceinline__ float fexp2(float x) {
    return __builtin_amdgcn_exp2f(x);   // raw v_exp_f32 (2^x)
}

// LDS rows are 64 bf16 (128 B). XOR-swizzle 16B slot by row (G4 fix).
__device__ __forceinline__ int swzE(int row, int e) {
    return row * 64 + (e ^ ((row & 7) << 3));
}

__device__ __forceinline__ void split2(float f, bf16& h, bf16& l) {
    bf16 hh = (bf16)f;
    h = hh;
    l = (bf16)(f - (float)hh);
}

// Load 8 contiguous fp32, scale, split into hi/lo bf16x8.
__device__ __forceinline__ void split8(const float* __restrict__ p, float scale,
                                       bf16x8& h, bf16x8& l) {
    const float4 v0 = *(const float4*)p;
    const float4 v1 = *(const float4*)(p + 4);
    float f0 = v0.x * scale, f1 = v0.y * scale, f2 = v0.z * scale, f3 = v0.w * scale;
    float f4 = v1.x * scale, f5 = v1.y * scale, f6 = v1.z * scale, f7 = v1.w * scale;
    bf16 h0 = (bf16)f0, h1 = (bf16)f1, h2 = (bf16)f2, h3 = (bf16)f3;
    bf16 h4 = (bf16)f4, h5 = (bf16)f5, h6 = (bf16)f6, h7 = (bf16)f7;
    h = (bf16x8){h0, h1, h2, h3, h4, h5, h6, h7};
    l = (bf16x8){(bf16)(f0 - (float)h0), (bf16)(f1 - (float)h1),
                 (bf16)(f2 - (float)h2), (bf16)(f3 - (float)h3),
                 (bf16)(f4 - (float)h4), (bf16)(f5 - (float)h5),
                 (bf16)(f6 - (float)h6), (bf16)(f7 - (float)h7)};
}

// ---------------------------------------------------------------------------
// Transpose + split weights: W[K][N] fp32 -> Wt_hi/lo[N][K] bf16.
// ---------------------------------------------------------------------------
__global__ __launch_bounds__(256)
void prep_w(const float* __restrict__ W, bf16* __restrict__ Wth,
            bf16* __restrict__ Wtl, int K, int N) {
    __shared__ float T[64][65];
    const int k0 = blockIdx.x * 64, n0 = blockIdx.y * 64;
    const int t = threadIdx.x;
    #pragma unroll
    for (int i = 0; i < 4; ++i) {
        int r = i * 16 + (t >> 4);
        int c = (t & 15) * 4;
        float4 v = *(const float4*)&W[(size_t)(k0 + r) * N + n0 + c];
        T[r][c + 0] = v.x; T[r][c + 1] = v.y; T[r][c + 2] = v.z; T[r][c + 3] = v.w;
    }
    __syncthreads();
    #pragma unroll
    for (int i = 0; i < 4; ++i) {
        int n = i * 16 + (t >> 4);
        int c = (t & 15) * 4;
        float a0 = T[c + 0][n], a1 = T[c + 1][n], a2 = T[c + 2][n], a3 = T[c + 3][n];
        bf16 h0 = (bf16)a0, h1 = (bf16)a1, h2 = (bf16)a2, h3 = (bf16)a3;
        bf16x4 hv = (bf16x4){h0, h1, h2, h3};
        bf16x4 lv = (bf16x4){(bf16)(a0 - (float)h0), (bf16)(a1 - (float)h1),
                             (bf16)(a2 - (float)h2), (bf16)(a3 - (float)h3)};
        *(bf16x4*)&Wth[(size_t)(n0 + n) * K + k0 + c] = hv;
        *(bf16x4*)&Wtl[(size_t)(n0 + n) * K + k0 + c] = lv;
    }
}

// ---------------------------------------------------------------------------
// Split-bf16 MFMA GEMM: C[M,N] fp32 = A[M,K] fp32 @ Bt[N,K]^T (pre-split bf16).
// 128x128 tile, BK=64, 4 waves of 64x64 (4x4 16x16x32 frags), 3-term split.
// ---------------------------------------------------------------------------
__global__ __launch_bounds__(256, 2)
void gemm_split(const float* __restrict__ A, const bf16* __restrict__ Bth,
                const bf16* __restrict__ Btl, float* __restrict__ C,
                int M, int N, int K) {
    __shared__ bf16 Ah[128 * 64], Al[128 * 64], Bh[128 * 64], Bl[128 * 64];
    const int t = threadIdx.x;
    const int lane = t & 63, w = t >> 6;
    const int l15 = lane & 15, g = lane >> 4;
    const int wm = (w >> 1) * 64, wn = (w & 1) * 64;
    const int rowA = blockIdx.y * 128;
    const int colB = blockIdx.x * 128;
    const int sr = t >> 1;          // staging row 0..127
    const int sc = (t & 1) * 32;    // staging k-chunk

    f32x4 acc[4][4] = {};

    for (int k0 = 0; k0 < K; k0 += 64) {
        __syncthreads();
        #pragma unroll
        for (int u = 0; u < 4; ++u) {   // A: fp32 -> hi/lo
            bf16x8 h, l;
            split8(&A[(size_t)(rowA + sr) * K + k0 + sc + u * 8], 1.0f, h, l);
            int off = swzE(sr, sc + u * 8);
            *(bf16x8*)&Ah[off] = h;
            *(bf16x8*)&Al[off] = l;
        }
        #pragma unroll
        for (int u = 0; u < 4; ++u) {   // B: pre-split copy
            int off = swzE(sr, sc + u * 8);
            *(bf16x8*)&Bh[off] = *(const bf16x8*)&Bth[(size_t)(colB + sr) * K + k0 + sc + u * 8];
            *(bf16x8*)&Bl[off] = *(const bf16x8*)&Btl[(size_t)(colB + sr) * K + k0 + sc + u * 8];
        }
        __syncthreads();
        #pragma unroll
        for (int kst = 0; kst < 2; ++kst) {
            bf16x8 ah[4], al[4];
            #pragma unroll
            for (int mi = 0; mi < 4; ++mi) {
                int off = swzE(wm + mi * 16 + l15, kst * 32 + g * 8);
                ah[mi] = *(const bf16x8*)&Ah[off];
                al[mi] = *(const bf16x8*)&Al[off];
            }
            #pragma unroll
            for (int ni = 0; ni < 4; ++ni) {
                int off = swzE(wn + ni * 16 + l15, kst * 32 + g * 8);
                bf16x8 bh = *(const bf16x8*)&Bh[off];
                bf16x8 bl = *(const bf16x8*)&Bl[off];
                #pragma unroll
                for (int mi = 0; mi < 4; ++mi) {
                    acc[mi][ni] = mfma16(ah[mi], bh, acc[mi][ni]);
                    acc[mi][ni] = mfma16(ah[mi], bl, acc[mi][ni]);
                    acc[mi][ni] = mfma16(al[mi], bh, acc[mi][ni]);
                }
            }
        }
    }
    #pragma unroll
    for (int mi = 0; mi < 4; ++mi)
        #pragma unroll
        for (int ni = 0; ni < 4; ++ni)
            #pragma unroll
            for (int r = 0; r < 4; ++r) {
                int row = rowA + wm + mi * 16 + g * 4 + r;
                int col = colB + wn + ni * 16 + l15;
                C[(size_t)row * N + col] = acc[mi][ni][r];
            }
}

// ---------------------------------------------------------------------------
// Convert K,V from fp32 qkv to split bf16. K: [bh][s][d] hi/lo. V: transposed
// AND slot-permuted [bh][d][slot], slot = (s&15)*4 + ((s>>4)&3) within each
// 64-block — the same permutation the flash kernel uses for P, so PV is exact.
// ---------------------------------------------------------------------------
__global__ __launch_bounds__(256)
void convert_kv(const float* __restrict__ qkv,
                bf16* __restrict__ Kh, bf16* __restrict__ Kl,
                bf16* __restrict__ Vth, bf16* __restrict__ Vtl) {
    const int st = blockIdx.x, h = blockIdx.y, b = blockIdx.z;
    const int bh = b * NH + h;
    __shared__ float VT[64][68];
    const int t = threadIdx.x;
    const int r = t >> 2, c16 = (t & 3) * 16;

    // K rows
    const size_t kbase = ((size_t)(b * SEQ + st * 64 + r) * 3 + 1) * DM + h * DK;
    #pragma unroll
    for (int u = 0; u < 2; ++u) {
        bf16x8 hh, ll;
        split8(&qkv[kbase + c16 + u * 8], 1.0f, hh, ll);
        size_t o = ((size_t)bh * SEQ + st * 64 + r) * DK + c16 + u * 8;
        *(bf16x8*)&Kh[o] = hh;
        *(bf16x8*)&Kl[o] = ll;
    }
    // V -> LDS fp32
    const size_t vbase = ((size_t)(b * SEQ + st * 64 + r) * 3 + 2) * DM + h * DK;
    #pragma unroll
    for (int u = 0; u < 4; ++u) {
        float4 v = *(const float4*)&qkv[vbase + c16 + u * 4];
        VT[r][c16 + u * 4 + 0] = v.x; VT[r][c16 + u * 4 + 1] = v.y;
        VT[r][c16 + u * 4 + 2] = v.z; VT[r][c16 + u * 4 + 3] = v.w;
    }
    __syncthreads();
    // transposed + permuted write: thread owns d=r, slots c16..c16+15
    bf16x8 vh0{}, vh1{}, vl0{}, vl1{};
    #pragma unroll
    for (int i = 0; i < 8; ++i) {
        int slot = c16 + i;
        float f = VT[(slot & 3) * 16 + (slot >> 2)][r];
        bf16 hh = (bf16)f;
        vh0[i] = hh; vl0[i] = (bf16)(f - (float)hh);
    }
    #pragma unroll
    for (int i = 0; i < 8; ++i) {
        int slot = c16 + 8 + i;
        float f = VT[(slot & 3) * 16 + (slot >> 2)][r];
        bf16 hh = (bf16)f;
        vh1[i] = hh; vl1[i] = (bf16)(f - (float)hh);
    }
    size_t vo = ((size_t)bh * DK + r) * SEQ + st * 64 + c16;
    *(bf16x8*)&Vth[vo] = vh0;     *(bf16x8*)&Vth[vo + 8] = vh1;
    *(bf16x8*)&Vtl[vo] = vl0;     *(bf16x8*)&Vtl[vo + 8] = vl1;
}

// ---------------------------------------------------------------------------
// MFMA flash attention. Block = 128 q-rows of one (b,h); 4 waves, each wave
// owns 32 q-rows. K/V tile = 64. 3-term split on QK^T and PV. Q in registers.
// R4: hi-only LDS staging (lo fragments direct from L2) -> 48 KB LDS,
// 3 blocks/CU; exp2-domain softmax; defer-max (THR=8 log2 units).
// ---------------------------------------------------------------------------
__global__ __launch_bounds__(256, 3)
void flash_mfma(const float* __restrict__ qkv,
                const bf16* __restrict__ Kh, const bf16* __restrict__ Kl,
                const bf16* __restrict__ Vth, const bf16* __restrict__ Vtl,
                float* __restrict__ att) {
    // XCD-bijective swizzle: nwg = 512 (divisible by 8).
    const int nwg = (int)gridDim.x;
    const int cpx = nwg >> 3;
    const int bid = (int)blockIdx.x;
    const int wg = (bid & 7) * cpx + (bid >> 3);
    const int qt = wg & 31;
    const int bh = wg >> 5;
    const int h = bh & 7, b = bh >> 3;

    __shared__ bf16 KhS[64 * 64], VhS[64 * 64];       // 16 KB
    __shared__ bf16 PhS[128 * 64], PlS[128 * 64];     // 32 KB

    const int t = threadIdx.x, lane = t & 63, w = t >> 6;
    const int l15 = lane & 15, g = lane >> 4;
    const int q0 = qt * 128;
    const int wq = w * 32;

    const float LOG2E = 1.44269504088896f;

    // Q fragments in registers (scaled by log2e/8, split hi/lo)
    bf16x8 qh[2][2], ql[2][2];
    #pragma unroll
    for (int mi = 0; mi < 2; ++mi) {
        const int row = q0 + wq + mi * 16 + l15;
        const size_t base = ((size_t)(b * SEQ + row) * 3 + 0) * DM + h * DK + g * 8;
        #pragma unroll
        for (int kst = 0; kst < 2; ++kst)
            split8(&qkv[base + kst * 32], 0.125f * LOG2E, qh[mi][kst], ql[mi][kst]);
    }

    float m_run[2][4], l_run[2][4];
    f32x4 o[2][4] = {};
    #pragma unroll
    for (int mi = 0; mi < 2; ++mi)
        #pragma unroll
        for (int r = 0; r < 4; ++r) { m_run[mi][r] = -1e30f; l_run[mi][r] = 0.f; }

    const int sr = t >> 2, sc16 = (t & 3) * 16;
    // per-lane fragment base addresses for direct-global lo reads
    const size_t kfb = ((size_t)bh * SEQ + l15) * DK + g * 8;
    const size_t vfb = ((size_t)bh * DK + l15) * SEQ + g * 8;

    for (int kt = 0; kt < SEQ / 64; ++kt) {
        __syncthreads();   // prev tile's KhS/VhS reads done
        // ---- stage hi K/V only ----
        {
            const size_t ko = ((size_t)bh * SEQ + kt * 64 + sr) * DK + sc16;
            const size_t vo = ((size_t)bh * DK + sr) * SEQ + kt * 64 + sc16;
            #pragma unroll
            for (int u = 0; u < 2; ++u) {
                int off = swzE(sr, sc16 + u * 8);
                *(bf16x8*)&KhS[off] = *(const bf16x8*)&Kh[ko + u * 8];
                *(bf16x8*)&VhS[off] = *(const bf16x8*)&Vth[vo + u * 8];
            }
        }
        __syncthreads();

        // ---- scores: 3-term split; lo term fed straight from L2 ----
        f32x4 s[2][4] = {};
        #pragma unroll
        for (int kst = 0; kst < 2; ++kst) {
            bf16x8 kl[4];
            #pragma unroll
            for (int ni = 0; ni < 4; ++ni)
                kl[ni] = *(const bf16x8*)&Kl[kfb + (size_t)(kt * 64 + ni * 16) * DK + kst * 32];
            #pragma unroll
            for (int ni = 0; ni < 4; ++ni) {
                int off = swzE(ni * 16 + l15, kst * 32 + g * 8);
                bf16x8 kh = *(const bf16x8*)&KhS[off];
                #pragma unroll
                for (int mi = 0; mi < 2; ++mi) {
                    s[mi][ni] = mfma16(qh[mi][kst], kh, s[mi][ni]);
                    s[mi][ni] = mfma16(ql[mi][kst], kh, s[mi][ni]);
                }
            }
            #pragma unroll
            for (int ni = 0; ni < 4; ++ni)
                #pragma unroll
                for (int mi = 0; mi < 2; ++mi)
                    s[mi][ni] = mfma16(qh[mi][kst], kl[ni], s[mi][ni]);
        }

        // ---- online softmax (exp2 domain) with defer-max ----
        #pragma unroll
        for (int mi = 0; mi < 2; ++mi) {
            #pragma unroll
            for (int r = 0; r < 4; ++r) {
                float mx = fmaxf(fmaxf(s[mi][0][r], s[mi][1][r]),
                                 fmaxf(s[mi][2][r], s[mi][3][r]));
                #pragma unroll
                for (int off = 1; off < 16; off <<= 1)
                    mx = fmaxf(mx, __shfl_xor(mx, off));
                if (__any(mx - m_run[mi][r] > 8.0f)) {   // rescale needed
                    const float mnew  = fmaxf(m_run[mi][r], mx);
                    const float alpha = fexp2(m_run[mi][r] - mnew);
                    #pragma unroll
                    for (int ni = 0; ni < 4; ++ni) o[mi][ni][r] *= alpha;
                    l_run[mi][r] *= alpha;
                    m_run[mi][r] = mnew;
                }
                float p0 = fexp2(s[mi][0][r] - m_run[mi][r]);
                float p1 = fexp2(s[mi][1][r] - m_run[mi][r]);
                float p2 = fexp2(s[mi][2][r] - m_run[mi][r]);
                float p3 = fexp2(s[mi][3][r] - m_run[mi][r]);
                float rs = (p0 + p1) + (p2 + p3);
                #pragma unroll
                for (int off = 1; off < 16; off <<= 1)
                    rs += __shfl_xor(rs, off);
                l_run[mi][r] += rs;

                bf16 h0, l0, h1, l1, h2, l2, h3, l3;
                split2(p0, h0, l0); split2(p1, h1, l1);
                split2(p2, h2, l2); split2(p3, h3, l3);
                const int prow = wq + mi * 16 + g * 4 + r;
                const int e = swzE(prow, l15 * 4);
                *(bf16x4*)&PhS[e] = (bf16x4){h0, h1, h2, h3};
                *(bf16x4*)&PlS[e] = (bf16x4){l0, l1, l2, l3};
            }
        }
        // P is wave-private (same wave writes & reads its 32 rows): no barrier.

        // ---- O += P @ V (3-term split; vl direct from L2) ----
        #pragma unroll
        for (int kst = 0; kst < 2; ++kst) {
            bf16x8 vl[4];
            #pragma unroll
            for (int ni = 0; ni < 4; ++ni)
                vl[ni] = *(const bf16x8*)&Vtl[vfb + (size_t)(ni * 16) * SEQ + kt * 64 + kst * 32];
            bf16x8 ph[2], pl[2];
            #pragma unroll
            for (int mi = 0; mi < 2; ++mi) {
                int off = swzE(wq + mi * 16 + l15, kst * 32 + g * 8);
                ph[mi] = *(const bf16x8*)&PhS[off];
                pl[mi] = *(const bf16x8*)&PlS[off];
            }
            #pragma unroll
            for (int ni = 0; ni < 4; ++ni) {
                int off = swzE(ni * 16 + l15, kst * 32 + g * 8);
                bf16x8 vh = *(const bf16x8*)&VhS[off];
                #pragma unroll
                for (int mi = 0; mi < 2; ++mi) {
                    o[mi][ni] = mfma16(ph[mi], vh, o[mi][ni]);
                    o[mi][ni] = mfma16(pl[mi], vh, o[mi][ni]);
                }
            }
            #pragma unroll
            for (int ni = 0; ni < 4; ++ni)
                #pragma unroll
                for (int mi = 0; mi < 2; ++mi)
                    o[mi][ni] = mfma16(ph[mi], vl[ni], o[mi][ni]);
        }
    }

    // ---- epilogue ----
    #pragma unroll
    for (int mi = 0; mi < 2; ++mi)
        #pragma unroll
        for (int r = 0; r < 4; ++r) {
            const float inv = 1.0f / l_run[mi][r];
            const int row = q0 + wq + mi * 16 + g * 4 + r;
            #pragma unroll
            for (int ni = 0; ni < 4; ++ni)
                att[(size_t)(b * SEQ + row) * DM + h * DK + ni * 16 + l15] =
                    o[mi][ni][r] * inv;
        }
}

// ---------------------------------------------------------------------------
extern "C" void kernel_launch(void* const* d_in, const int* in_sizes, int n_in,
                              void* d_out, int out_size, void* d_ws, size_t ws_size,
                              hipStream_t stream) {
    const float* x    = (const float*)d_in[0];
    const float* Wqkv = (const float*)d_in[1];
    const float* Wout = (const float*)d_in[2];
    float* out = (float*)d_out;

    char* ws = (char*)d_ws;
    float* qkv  = (float*)(ws);                          // 48 MB
    float* attn = (float*)(ws + (size_t)48 * 1048576);   // 16 MB
    bf16* Khp  = (bf16*)(ws + (size_t)64 * 1048576);     // 8 MB
    bf16* Klp  = (bf16*)(ws + (size_t)72 * 1048576);     // 8 MB
    bf16* Vthp = (bf16*)(ws + (size_t)80 * 1048576);     // 8 MB
    bf16* Vtlp = (bf16*)(ws + (size_t)88 * 1048576);     // 8 MB
    bf16* Wqh  = (bf16*)(ws + (size_t)96 * 1048576);     // 1.5 MB
    bf16* Wql  = (bf16*)(ws + (size_t)98 * 1048576);
    bf16* Woh  = (bf16*)(ws + (size_t)100 * 1048576);    // 0.5 MB
    bf16* Wol  = (bf16*)(ws + (size_t)101 * 1048576);

    const int M = NB * SEQ;   // 8192

    prep_w<<<dim3(DM / 64, (3 * DM) / 64), 256, 0, stream>>>(Wqkv, Wqh, Wql, DM, 3 * DM);
    prep_w<<<dim3(DM / 64, DM / 64), 256, 0, stream>>>(Wout, Woh, Wol, DM, DM);

    gemm_split<<<dim3((3 * DM) / 128, M / 128), 256, 0, stream>>>(
        x, Wqh, Wql, qkv, M, 3 * DM, DM);

    convert_kv<<<dim3(SEQ / 64, NH, NB), 256, 0, stream>>>(qkv, Khp, Klp, Vthp, Vtlp);

    flash_mfma<<<dim3((SEQ / 128) * NH * NB), 256, 0, stream>>>(
        qkv, Khp, Klp, Vthp, Vtlp, attn);

    gemm_split<<<dim3(DM / 128, M / 128), 256, 0, stream>>>(
        attn, Woh, Wol, out, M, DM, DM);
}

// Round 5
// 390.035 us; speedup vs baseline: 1.2462x; 1.2462x over previous
//
#include <hip/hip_runtime.h>
#include <hip/hip_bf16.h>

#define SEQ 4096
#define NB 2
#define DM 512
#define NH 8
#define DK 64

typedef __bf16 bf16;
typedef __bf16 bf16x4 __attribute__((ext_vector_type(4)));
typedef __bf16 bf16x8 __attribute__((ext_vector_type(8)));
typedef float  f32x4 __attribute__((ext_vector_type(4)));

__device__ __forceinline__ f32x4 mfma16(bf16x8 a, bf16x8 b, f32x4 c) {
    return __builtin_amdgcn_mfma_f32_16x16x32_bf16(a, b, c, 0, 0, 0);
}

__device__ __forceinline__ float fexp2(float x) {
    return __builtin_amdgcn_exp2f(x);   // raw v_exp_f32 (2^x)
}

// LDS rows are 64 bf16 (128 B). XOR-swizzle 16B slot by row (G4 fix).
__device__ __forceinline__ int swzE(int row, int e) {
    return row * 64 + (e ^ ((row & 7) << 3));
}

__device__ __forceinline__ void split2(float f, bf16& h, bf16& l) {
    bf16 hh = (bf16)f;
    h = hh;
    l = (bf16)(f - (float)hh);
}

// Load 8 contiguous fp32, scale, split into hi/lo bf16x8.
__device__ __forceinline__ void split8(const float* __restrict__ p, float scale,
                                       bf16x8& h, bf16x8& l) {
    const float4 v0 = *(const float4*)p;
    const float4 v1 = *(const float4*)(p + 4);
    float f0 = v0.x * scale, f1 = v0.y * scale, f2 = v0.z * scale, f3 = v0.w * scale;
    float f4 = v1.x * scale, f5 = v1.y * scale, f6 = v1.z * scale, f7 = v1.w * scale;
    bf16 h0 = (bf16)f0, h1 = (bf16)f1, h2 = (bf16)f2, h3 = (bf16)f3;
    bf16 h4 = (bf16)f4, h5 = (bf16)f5, h6 = (bf16)f6, h7 = (bf16)f7;
    h = (bf16x8){h0, h1, h2, h3, h4, h5, h6, h7};
    l = (bf16x8){(bf16)(f0 - (float)h0), (bf16)(f1 - (float)h1),
                 (bf16)(f2 - (float)h2), (bf16)(f3 - (float)h3),
                 (bf16)(f4 - (float)h4), (bf16)(f5 - (float)h5),
                 (bf16)(f6 - (float)h6), (bf16)(f7 - (float)h7)};
}

// ---------------------------------------------------------------------------
// Transpose + split weights: W[K][N] fp32 -> Wt_hi/lo[N][K] bf16.
// ---------------------------------------------------------------------------
__global__ __launch_bounds__(256)
void prep_w(const float* __restrict__ W, bf16* __restrict__ Wth,
            bf16* __restrict__ Wtl, int K, int N) {
    __shared__ float T[64][65];
    const int k0 = blockIdx.x * 64, n0 = blockIdx.y * 64;
    const int t = threadIdx.x;
    #pragma unroll
    for (int i = 0; i < 4; ++i) {
        int r = i * 16 + (t >> 4);
        int c = (t & 15) * 4;
        float4 v = *(const float4*)&W[(size_t)(k0 + r) * N + n0 + c];
        T[r][c + 0] = v.x; T[r][c + 1] = v.y; T[r][c + 2] = v.z; T[r][c + 3] = v.w;
    }
    __syncthreads();
    #pragma unroll
    for (int i = 0; i < 4; ++i) {
        int n = i * 16 + (t >> 4);
        int c = (t & 15) * 4;
        float a0 = T[c + 0][n], a1 = T[c + 1][n], a2 = T[c + 2][n], a3 = T[c + 3][n];
        bf16 h0 = (bf16)a0, h1 = (bf16)a1, h2 = (bf16)a2, h3 = (bf16)a3;
        bf16x4 hv = (bf16x4){h0, h1, h2, h3};
        bf16x4 lv = (bf16x4){(bf16)(a0 - (float)h0), (bf16)(a1 - (float)h1),
                             (bf16)(a2 - (float)h2), (bf16)(a3 - (float)h3)};
        *(bf16x4*)&Wth[(size_t)(n0 + n) * K + k0 + c] = hv;
        *(bf16x4*)&Wtl[(size_t)(n0 + n) * K + k0 + c] = lv;
    }
}

// ---------------------------------------------------------------------------
// Split-bf16 MFMA GEMM: C[M,N] fp32 = A[M,K] fp32 @ Bt[N,K]^T (pre-split bf16).
// 128x128 tile, BK=64, 4 waves of 64x64 (4x4 16x16x32 frags), 3-term split.
// ---------------------------------------------------------------------------
__global__ __launch_bounds__(256, 2)
void gemm_split(const float* __restrict__ A, const bf16* __restrict__ Bth,
                const bf16* __restrict__ Btl, float* __restrict__ C,
                int M, int N, int K) {
    __shared__ bf16 Ah[128 * 64], Al[128 * 64], Bh[128 * 64], Bl[128 * 64];
    const int t = threadIdx.x;
    const int lane = t & 63, w = t >> 6;
    const int l15 = lane & 15, g = lane >> 4;
    const int wm = (w >> 1) * 64, wn = (w & 1) * 64;
    const int rowA = blockIdx.y * 128;
    const int colB = blockIdx.x * 128;
    const int sr = t >> 1;          // staging row 0..127
    const int sc = (t & 1) * 32;    // staging k-chunk

    f32x4 acc[4][4] = {};

    for (int k0 = 0; k0 < K; k0 += 64) {
        __syncthreads();
        #pragma unroll
        for (int u = 0; u < 4; ++u) {   // A: fp32 -> hi/lo
            bf16x8 h, l;
            split8(&A[(size_t)(rowA + sr) * K + k0 + sc + u * 8], 1.0f, h, l);
            int off = swzE(sr, sc + u * 8);
            *(bf16x8*)&Ah[off] = h;
            *(bf16x8*)&Al[off] = l;
        }
        #pragma unroll
        for (int u = 0; u < 4; ++u) {   // B: pre-split copy
            int off = swzE(sr, sc + u * 8);
            *(bf16x8*)&Bh[off] = *(const bf16x8*)&Bth[(size_t)(colB + sr) * K + k0 + sc + u * 8];
            *(bf16x8*)&Bl[off] = *(const bf16x8*)&Btl[(size_t)(colB + sr) * K + k0 + sc + u * 8];
        }
        __syncthreads();
        #pragma unroll
        for (int kst = 0; kst < 2; ++kst) {
            bf16x8 ah[4], al[4];
            #pragma unroll
            for (int mi = 0; mi < 4; ++mi) {
                int off = swzE(wm + mi * 16 + l15, kst * 32 + g * 8);
                ah[mi] = *(const bf16x8*)&Ah[off];
                al[mi] = *(const bf16x8*)&Al[off];
            }
            #pragma unroll
            for (int ni = 0; ni < 4; ++ni) {
                int off = swzE(wn + ni * 16 + l15, kst * 32 + g * 8);
                bf16x8 bh = *(const bf16x8*)&Bh[off];
                bf16x8 bl = *(const bf16x8*)&Bl[off];
                #pragma unroll
                for (int mi = 0; mi < 4; ++mi) {
                    acc[mi][ni] = mfma16(ah[mi], bh, acc[mi][ni]);
                    acc[mi][ni] = mfma16(ah[mi], bl, acc[mi][ni]);
                    acc[mi][ni] = mfma16(al[mi], bh, acc[mi][ni]);
                }
            }
        }
    }
    #pragma unroll
    for (int mi = 0; mi < 4; ++mi)
        #pragma unroll
        for (int ni = 0; ni < 4; ++ni)
            #pragma unroll
            for (int r = 0; r < 4; ++r) {
                int row = rowA + wm + mi * 16 + g * 4 + r;
                int col = colB + wn + ni * 16 + l15;
                C[(size_t)row * N + col] = acc[mi][ni][r];
            }
}

// ---------------------------------------------------------------------------
// Convert K,V from fp32 qkv to split bf16. K: [bh][s][d] hi/lo. V: transposed
// AND slot-permuted [bh][d][slot], slot = (s&15)*4 + ((s>>4)&3) within each
// 64-block — the same permutation the flash kernel uses for P, so PV is exact.
// ---------------------------------------------------------------------------
__global__ __launch_bounds__(256)
void convert_kv(const float* __restrict__ qkv,
                bf16* __restrict__ Kh, bf16* __restrict__ Kl,
                bf16* __restrict__ Vth, bf16* __restrict__ Vtl) {
    const int st = blockIdx.x, h = blockIdx.y, b = blockIdx.z;
    const int bh = b * NH + h;
    __shared__ float VT[64][68];
    const int t = threadIdx.x;
    const int r = t >> 2, c16 = (t & 3) * 16;

    // K rows
    const size_t kbase = ((size_t)(b * SEQ + st * 64 + r) * 3 + 1) * DM + h * DK;
    #pragma unroll
    for (int u = 0; u < 2; ++u) {
        bf16x8 hh, ll;
        split8(&qkv[kbase + c16 + u * 8], 1.0f, hh, ll);
        size_t o = ((size_t)bh * SEQ + st * 64 + r) * DK + c16 + u * 8;
        *(bf16x8*)&Kh[o] = hh;
        *(bf16x8*)&Kl[o] = ll;
    }
    // V -> LDS fp32
    const size_t vbase = ((size_t)(b * SEQ + st * 64 + r) * 3 + 2) * DM + h * DK;
    #pragma unroll
    for (int u = 0; u < 4; ++u) {
        float4 v = *(const float4*)&qkv[vbase + c16 + u * 4];
        VT[r][c16 + u * 4 + 0] = v.x; VT[r][c16 + u * 4 + 1] = v.y;
        VT[r][c16 + u * 4 + 2] = v.z; VT[r][c16 + u * 4 + 3] = v.w;
    }
    __syncthreads();
    // transposed + permuted write: thread owns d=r, slots c16..c16+15
    bf16x8 vh0{}, vh1{}, vl0{}, vl1{};
    #pragma unroll
    for (int i = 0; i < 8; ++i) {
        int slot = c16 + i;
        float f = VT[(slot & 3) * 16 + (slot >> 2)][r];
        bf16 hh = (bf16)f;
        vh0[i] = hh; vl0[i] = (bf16)(f - (float)hh);
    }
    #pragma unroll
    for (int i = 0; i < 8; ++i) {
        int slot = c16 + 8 + i;
        float f = VT[(slot & 3) * 16 + (slot >> 2)][r];
        bf16 hh = (bf16)f;
        vh1[i] = hh; vl1[i] = (bf16)(f - (float)hh);
    }
    size_t vo = ((size_t)bh * DK + r) * SEQ + st * 64 + c16;
    *(bf16x8*)&Vth[vo] = vh0;     *(bf16x8*)&Vth[vo + 8] = vh1;
    *(bf16x8*)&Vtl[vo] = vl0;     *(bf16x8*)&Vtl[vo + 8] = vl1;
}

// ---------------------------------------------------------------------------
// MFMA flash attention. Block = 128 q-rows of one (b,h); 8 waves x 16 q-rows.
// K/V tile = 64, full hi+lo LDS staging (R3 structure), register prefetch of
// next tile, exp2-domain softmax with defer-max. 64 KB LDS -> 2 blocks/CU
// = 4 waves/SIMD (vs R3's 2).
// ---------------------------------------------------------------------------
__global__ __launch_bounds__(512, 4)
void flash_mfma(const float* __restrict__ qkv,
                const bf16* __restrict__ Kh, const bf16* __restrict__ Kl,
                const bf16* __restrict__ Vth, const bf16* __restrict__ Vtl,
                float* __restrict__ att) {
    // XCD-bijective swizzle: nwg = 512 (divisible by 8).
    const int nwg = (int)gridDim.x;
    const int cpx = nwg >> 3;
    const int bid = (int)blockIdx.x;
    const int wg = (bid & 7) * cpx + (bid >> 3);
    const int qt = wg & 31;
    const int bh = wg >> 5;
    const int h = bh & 7, b = bh >> 3;

    __shared__ bf16 KhS[64 * 64], KlS[64 * 64], VhS[64 * 64], VlS[64 * 64]; // 32 KB
    __shared__ bf16 PhS[128 * 64], PlS[128 * 64];                           // 32 KB

    const int t = threadIdx.x, lane = t & 63, w = t >> 6;   // 8 waves
    const int l15 = lane & 15, g = lane >> 4;
    const int q0 = qt * 128;
    const int wq = w * 16;   // each wave owns 16 q-rows

    const float LOG2E = 1.44269504088896f;

    // Q fragments in registers (scaled by log2e/8, split hi/lo)
    bf16x8 qh[2], ql[2];
    {
        const int row = q0 + wq + l15;
        const size_t base = ((size_t)(b * SEQ + row) * 3 + 0) * DM + h * DK + g * 8;
        split8(&qkv[base], 0.125f * LOG2E, qh[0], ql[0]);
        split8(&qkv[base + 32], 0.125f * LOG2E, qh[1], ql[1]);
    }

    float m_run[4], l_run[4];
    f32x4 o[4] = {};
    #pragma unroll
    for (int r = 0; r < 4; ++r) { m_run[r] = -1e30f; l_run[r] = 0.f; }

    // staging: 512 threads cover one 64x64 bf16 tile with one 16B load each
    const int sr = t >> 3, sc8 = (t & 7) * 8;
    const size_t kbase = ((size_t)bh * SEQ + sr) * DK + sc8;
    const size_t vbase = ((size_t)bh * DK + sr) * SEQ + sc8;

    const int NT = SEQ / 64;
    // prefetch tile 0 into registers
    bf16x8 rkh = *(const bf16x8*)&Kh[kbase];
    bf16x8 rkl = *(const bf16x8*)&Kl[kbase];
    bf16x8 rvh = *(const bf16x8*)&Vth[vbase];
    bf16x8 rvl = *(const bf16x8*)&Vtl[vbase];

    for (int kt = 0; kt < NT; ++kt) {
        __syncthreads();   // all waves done reading previous tile's LDS
        {
            const int soff = swzE(sr, sc8);
            *(bf16x8*)&KhS[soff] = rkh;
            *(bf16x8*)&KlS[soff] = rkl;
            *(bf16x8*)&VhS[soff] = rvh;
            *(bf16x8*)&VlS[soff] = rvl;
        }
        {   // issue next-tile loads; latency hides under this tile's compute
            const int nk = (kt + 1 < NT) ? kt + 1 : kt;
            rkh = *(const bf16x8*)&Kh[kbase + (size_t)nk * 64 * DK];
            rkl = *(const bf16x8*)&Kl[kbase + (size_t)nk * 64 * DK];
            rvh = *(const bf16x8*)&Vth[vbase + (size_t)nk * 64];
            rvl = *(const bf16x8*)&Vtl[vbase + (size_t)nk * 64];
        }
        __syncthreads();

        // ---- scores: 3-term split MFMA ----
        f32x4 s[4] = {};
        #pragma unroll
        for (int kst = 0; kst < 2; ++kst) {
            #pragma unroll
            for (int ni = 0; ni < 4; ++ni) {
                int off = swzE(ni * 16 + l15, kst * 32 + g * 8);
                bf16x8 kh_ = *(const bf16x8*)&KhS[off];
                bf16x8 kl_ = *(const bf16x8*)&KlS[off];
                s[ni] = mfma16(qh[kst], kh_, s[ni]);
                s[ni] = mfma16(ql[kst], kh_, s[ni]);
                s[ni] = mfma16(qh[kst], kl_, s[ni]);
            }
        }

        // ---- online softmax (exp2 domain) with defer-max ----
        #pragma unroll
        for (int r = 0; r < 4; ++r) {
            float mx = fmaxf(fmaxf(s[0][r], s[1][r]), fmaxf(s[2][r], s[3][r]));
            #pragma unroll
            for (int off = 1; off < 16; off <<= 1)
                mx = fmaxf(mx, __shfl_xor(mx, off));
            if (__any(mx - m_run[r] > 8.0f)) {
                const float mnew  = fmaxf(m_run[r], mx);
                const float alpha = fexp2(m_run[r] - mnew);
                #pragma unroll
                for (int ni = 0; ni < 4; ++ni) o[ni][r] *= alpha;
                l_run[r] *= alpha;
                m_run[r] = mnew;
            }
            float p0 = fexp2(s[0][r] - m_run[r]);
            float p1 = fexp2(s[1][r] - m_run[r]);
            float p2 = fexp2(s[2][r] - m_run[r]);
            float p3 = fexp2(s[3][r] - m_run[r]);
            float rs = (p0 + p1) + (p2 + p3);
            #pragma unroll
            for (int off = 1; off < 16; off <<= 1)
                rs += __shfl_xor(rs, off);
            l_run[r] += rs;

            bf16 h0, l0, h1, l1, h2, l2, h3, l3;
            split2(p0, h0, l0); split2(p1, h1, l1);
            split2(p2, h2, l2); split2(p3, h3, l3);
            const int prow = wq + g * 4 + r;
            const int e = swzE(prow, l15 * 4);
            *(bf16x4*)&PhS[e] = (bf16x4){h0, h1, h2, h3};
            *(bf16x4*)&PlS[e] = (bf16x4){l0, l1, l2, l3};
        }
        // P rows are wave-private: no barrier needed.

        // ---- O += P @ V (3-term split) ----
        #pragma unroll
        for (int kst = 0; kst < 2; ++kst) {
            const int poff = swzE(wq + l15, kst * 32 + g * 8);
            bf16x8 ph = *(const bf16x8*)&PhS[poff];
            bf16x8 pl = *(const bf16x8*)&PlS[poff];
            #pragma unroll
            for (int ni = 0; ni < 4; ++ni) {
                int off = swzE(ni * 16 + l15, kst * 32 + g * 8);
                bf16x8 vh_ = *(const bf16x8*)&VhS[off];
                bf16x8 vl_ = *(const bf16x8*)&VlS[off];
                o[ni] = mfma16(ph, vh_, o[ni]);
                o[ni] = mfma16(pl, vh_, o[ni]);
                o[ni] = mfma16(ph, vl_, o[ni]);
            }
        }
    }

    // ---- epilogue ----
    #pragma unroll
    for (int r = 0; r < 4; ++r) {
        const float inv = 1.0f / l_run[r];
        const int row = q0 + wq + g * 4 + r;
        #pragma unroll
        for (int ni = 0; ni < 4; ++ni)
            att[(size_t)(b * SEQ + row) * DM + h * DK + ni * 16 + l15] =
                o[ni][r] * inv;
    }
}

// ---------------------------------------------------------------------------
extern "C" void kernel_launch(void* const* d_in, const int* in_sizes, int n_in,
                              void* d_out, int out_size, void* d_ws, size_t ws_size,
                              hipStream_t stream) {
    const float* x    = (const float*)d_in[0];
    const float* Wqkv = (const float*)d_in[1];
    const float* Wout = (const float*)d_in[2];
    float* out = (float*)d_out;

    char* ws = (char*)d_ws;
    float* qkv  = (float*)(ws);                          // 48 MB
    float* attn = (float*)(ws + (size_t)48 * 1048576);   // 16 MB
    bf16* Khp  = (bf16*)(ws + (size_t)64 * 1048576);     // 8 MB
    bf16* Klp  = (bf16*)(ws + (size_t)72 * 1048576);     // 8 MB
    bf16* Vthp = (bf16*)(ws + (size_t)80 * 1048576);     // 8 MB
    bf16* Vtlp = (bf16*)(ws + (size_t)88 * 1048576);     // 8 MB
    bf16* Wqh  = (bf16*)(ws + (size_t)96 * 1048576);     // 1.5 MB
    bf16* Wql  = (bf16*)(ws + (size_t)98 * 1048576);
    bf16* Woh  = (bf16*)(ws + (size_t)100 * 1048576);    // 0.5 MB
    bf16* Wol  = (bf16*)(ws + (size_t)101 * 1048576);

    const int M = NB * SEQ;   // 8192

    prep_w<<<dim3(DM / 64, (3 * DM) / 64), 256, 0, stream>>>(Wqkv, Wqh, Wql, DM, 3 * DM);
    prep_w<<<dim3(DM / 64, DM / 64), 256, 0, stream>>>(Wout, Woh, Wol, DM, DM);

    gemm_split<<<dim3((3 * DM) / 128, M / 128), 256, 0, stream>>>(
        x, Wqh, Wql, qkv, M, 3 * DM, DM);

    convert_kv<<<dim3(SEQ / 64, NH, NB), 256, 0, stream>>>(qkv, Khp, Klp, Vthp, Vtlp);

    flash_mfma<<<dim3((SEQ / 128) * NH * NB), 512, 0, stream>>>(
        qkv, Khp, Klp, Vthp, Vtlp, attn);

    gemm_split<<<dim3(DM / 128, M / 128), 256, 0, stream>>>(
        attn, Woh, Wol, out, M, DM, DM);
}